// Round 1
// baseline (313.468 us; speedup 1.0000x reference)
//
#include <hip/hip_runtime.h>
#include <hip/hip_bf16.h>
#include <math.h>

typedef unsigned short u16;
typedef float float4e __attribute__((ext_vector_type(4)));
typedef short short8 __attribute__((ext_vector_type(8)));

#define SEQ 2048
#define DIM 512
#define NB  4

__device__ __forceinline__ float bf2f(u16 h) {
    return __uint_as_float(((unsigned)h) << 16);
}
__device__ __forceinline__ u16 f2bf(float f) {
    __hip_bfloat16 h = __float2bfloat16(f);
    return *reinterpret_cast<u16*>(&h);
}
__device__ __forceinline__ float curv_of(float raw) {
    // k_min + (k_max-k_min)*(tanh(raw)+1)/2, bounds (-2,2)
    return -2.0f + 2.0f * (tanhf(raw) + 1.0f);
}

// ---------------- f32 -> bf16 conversion ----------------
__global__ void cvt_bf16_kernel(const float* __restrict__ src, u16* __restrict__ dst, int n) {
    int i = blockIdx.x * blockDim.x + threadIdx.x;
    if (i < n) dst[i] = f2bf(src[i]);
}

// ---------------- GEMM (NT): C = A[M,K] * Bt[N,K]^T, bf16 MFMA ----------------
// MODE 0: QKV  -> C is u16 (bf16), epilogue adds bias (bq|bk|bv by column range)
// MODE 1: scores -> C is f32, causal block skip, distance-transform epilogue
// MODE 2: PV   -> C is f32, causal K-cap ((bm+1)*128)
template<int MODE>
__global__ __launch_bounds__(256) void gemm_nt_kernel(
    const u16* __restrict__ A, int lda, long long sA,
    const u16* __restrict__ Bt, int ldb, long long sB,
    void* __restrict__ Cv, int ldc, long long sC,
    int K,
    const float* __restrict__ bq, const float* __restrict__ bk, const float* __restrict__ bv,
    const float* __restrict__ qn2v, const float* __restrict__ kn2v,
    const float* __restrict__ curvp, const float* __restrict__ tempp)
{
    int bn = blockIdx.x, bm = blockIdx.y, b = blockIdx.z;
    if (MODE == 1 && bn > bm) return;   // causal: whole tile masked

    const u16* Ab = A + (size_t)b * sA;
    const u16* Bb = Bt + (size_t)b * sB;

    __shared__ __align__(16) u16 As[128 * 32];
    __shared__ __align__(16) u16 Bs[128 * 32];

    int t = threadIdx.x;
    int wave = t >> 6, lane = t & 63;
    int wm = wave >> 1, wn = wave & 1;
    int lrow = lane & 15, quad = lane >> 4;

    float4e acc[4][4];
#pragma unroll
    for (int i = 0; i < 4; i++)
#pragma unroll
        for (int j = 0; j < 4; j++)
            acc[i][j] = (float4e){0.f, 0.f, 0.f, 0.f};

    int kIters = (MODE == 2) ? ((bm + 1) * 4) : (K >> 5);

    int srow = t >> 2;   // 0..63
    int sch  = t & 3;    // 16B chunk within 64B row

    for (int kt = 0; kt < kIters; ++kt) {
        int k0 = kt << 5;
        __syncthreads();
#pragma unroll
        for (int h = 0; h < 2; h++) {
            int row = srow + h * 64;
            const u16* gA = Ab + (size_t)(bm * 128 + row) * lda + k0 + sch * 8;
            *(int4*)&As[row * 32 + sch * 8] = *(const int4*)gA;
            const u16* gB = Bb + (size_t)(bn * 128 + row) * ldb + k0 + sch * 8;
            *(int4*)&Bs[row * 32 + sch * 8] = *(const int4*)gB;
        }
        __syncthreads();

        short8 af[4], bf[4];
#pragma unroll
        for (int im = 0; im < 4; im++)
            af[im] = *(const short8*)&As[(wm * 64 + im * 16 + lrow) * 32 + quad * 8];
#pragma unroll
        for (int in = 0; in < 4; in++)
            bf[in] = *(const short8*)&Bs[(wn * 64 + in * 16 + lrow) * 32 + quad * 8];
#pragma unroll
        for (int im = 0; im < 4; im++)
#pragma unroll
            for (int in = 0; in < 4; in++)
                acc[im][in] = __builtin_amdgcn_mfma_f32_16x16x32_bf16(af[im], bf[in], acc[im][in], 0, 0, 0);
    }

    // ---------------- epilogue ----------------
    float kv = 0.f, absk = 0.f, sk = 1.f, invT = 1.f;
    if (MODE == 1) {
        kv = curv_of(curvp[0]);
        absk = fabsf(kv);
        sk = sqrtf(fmaxf(absk, 1e-5f));
        invT = 1.0f / (tempp[0] + 1e-8f);
    }

#pragma unroll
    for (int im = 0; im < 4; im++) {
#pragma unroll
        for (int in = 0; in < 4; in++) {
#pragma unroll
            for (int r = 0; r < 4; r++) {
                int i = bm * 128 + wm * 64 + im * 16 + quad * 4 + r;   // C row (m)
                int j = bn * 128 + wn * 64 + in * 16 + lrow;           // C col (n)
                float val = acc[im][in][r];
                if (MODE == 0) {
                    float bias = (j < 512) ? bq[j] : (j < 1024 ? bk[j - 512] : bv[j - 1024]);
                    u16* Cb = ((u16*)Cv) + (size_t)b * sC;
                    Cb[(size_t)i * ldc + j] = f2bf(val + bias);
                } else if (MODE == 1) {
                    if (j <= i) {
                        float qn = qn2v[b * SEQ + i];
                        float kn = kn2v[b * SEQ + j];
                        float dot = val;
                        float diff2 = fmaxf(qn + kn - 2.f * dot, 0.f);
                        float dist;
                        if (absk < 0.01f) {
                            dist = sqrtf(diff2 + 1e-12f);
                        } else if (kv < 0.f) {
                            float denom = fmaxf((1.f - absk * qn) * (1.f - absk * kn), 1e-5f);
                            float arg = fmaxf(1.f + 2.f * absk * diff2 / denom, 1.f + 1e-7f);
                            dist = acoshf(arg) / sk;
                        } else {
                            float c = fminf(fmaxf(absk * dot, -1.f + 1e-7f), 1.f - 1e-7f);
                            dist = acosf(c) / sk;
                        }
                        float* Cb = ((float*)Cv) + (size_t)b * sC;
                        Cb[(size_t)i * ldc + j] = -dist * invT;
                    }
                } else {
                    float* Cb = ((float*)Cv) + (size_t)b * sC;
                    Cb[(size_t)i * ldc + j] = val;
                }
            }
        }
    }
}

// ---------------- projection: norms + manifold scale, qkv_h (bf16) -> qm/km (bf16) ----------------
__global__ __launch_bounds__(256) void project_kernel(
    const u16* __restrict__ qkvh,   // [8192][1536] bf16
    u16* __restrict__ qm, u16* __restrict__ km,
    float* __restrict__ qn2, float* __restrict__ kn2,
    const float* __restrict__ curvp)
{
    int r = blockIdx.x;       // global row 0..8191
    int t = threadIdx.x;      // 256 threads
    float kv = curv_of(curvp[0]);
    float absk = fabsf(kv);
    float sk = sqrtf(fmaxf(absk, 1e-5f));

    const u16* qrow = qkvh + (size_t)r * 1536;
    const u16* krow = qrow + 512;
    float q0 = bf2f(qrow[t]),      q1 = bf2f(qrow[t + 256]);
    float k0 = bf2f(krow[t]),      k1 = bf2f(krow[t + 256]);

    float sq = q0 * q0 + q1 * q1;
    float s2 = k0 * k0 + k1 * k1;
#pragma unroll
    for (int off = 32; off > 0; off >>= 1) {
        sq += __shfl_down(sq, off);
        s2 += __shfl_down(s2, off);
    }
    __shared__ float rq[4], rk[4];
    int wave = t >> 6, lane = t & 63;
    if (lane == 0) { rq[wave] = sq; rk[wave] = s2; }
    __syncthreads();
    float n2q = rq[0] + rq[1] + rq[2] + rq[3];
    float n2k = rk[0] + rk[1] + rk[2] + rk[3];

    float sclq, sclk;
    {
        float nq = sqrtf(n2q + 1e-12f);
        float nk = sqrtf(n2k + 1e-12f);
        if (absk < 0.01f) { sclq = 1.f; sclk = 1.f; }
        else if (kv < 0.f) {
            float mx = (1.0f - 1e-3f) / sk;
            sclq = fminf(1.f, mx / nq);
            sclk = fminf(1.f, mx / nk);
        } else {
            sclq = 1.f / (nq * sk);
            sclk = 1.f / (nk * sk);
        }
    }
    if (t == 0) {
        qn2[r] = n2q * sclq * sclq;
        kn2[r] = n2k * sclk * sclk;
    }
    u16* qo = qm + (size_t)r * 512;
    u16* ko = km + (size_t)r * 512;
    qo[t]       = f2bf(q0 * sclq);
    qo[t + 256] = f2bf(q1 * sclq);
    ko[t]       = f2bf(k0 * sclk);
    ko[t + 256] = f2bf(k1 * sclk);
}

// ---------------- transpose v: qkv_h v-part [b][s][d] -> vT [b][d][s] (bf16) ----------------
__global__ __launch_bounds__(256) void transpose_v_kernel(
    const u16* __restrict__ qkvh, u16* __restrict__ vT)
{
    __shared__ u16 tile[32][33];
    int b = blockIdx.z;
    int s0 = blockIdx.x * 32, d0 = blockIdx.y * 32;
    int tx = threadIdx.x, ty = threadIdx.y;   // (32,8)
#pragma unroll
    for (int r = 0; r < 4; r++) {
        int s = s0 + ty + r * 8;
        tile[ty + r * 8][tx] = qkvh[(size_t)(b * SEQ + s) * 1536 + 1024 + d0 + tx];
    }
    __syncthreads();
#pragma unroll
    for (int r = 0; r < 4; r++) {
        int d = d0 + ty + r * 8;
        int s = s0 + tx;
        vT[((size_t)b * DIM + d) * SEQ + s] = tile[tx][ty + r * 8];
    }
}

// ---------------- softmax: one block per row; in-place normalize + bf16 copy ----------------
__global__ __launch_bounds__(256) void softmax_kernel(
    float* __restrict__ attnF,    // [B][S][S]  raw scores in, normalized out
    u16* __restrict__ attnH)      // [B][S][S]  bf16 out
{
    int i = blockIdx.x, b = blockIdx.y;
    int t = threadIdx.x;
    float* row = attnF + ((size_t)b * SEQ + i) * SEQ;
    u16* rowh = attnH + ((size_t)b * SEQ + i) * SEQ;
    int L = i + 1;

    __shared__ float buf[SEQ];
    __shared__ float redA[4], redB[4];
    int wave = t >> 6, lane = t & 63;

    float mx = -INFINITY;
    for (int j = t; j < L; j += 256) {
        float v = row[j];
        buf[j] = v;
        mx = fmaxf(mx, v);
    }
#pragma unroll
    for (int off = 32; off > 0; off >>= 1) mx = fmaxf(mx, __shfl_down(mx, off));
    if (lane == 0) redA[wave] = mx;
    __syncthreads();
    mx = fmaxf(fmaxf(redA[0], redA[1]), fmaxf(redA[2], redA[3]));

    float sum = 0.f;
    for (int j = t; j < L; j += 256) {
        float e = expf(buf[j] - mx);
        buf[j] = e;
        sum += e;
    }
#pragma unroll
    for (int off = 32; off > 0; off >>= 1) sum += __shfl_down(sum, off);
    if (lane == 0) redB[wave] = sum;
    __syncthreads();
    sum = redB[0] + redB[1] + redB[2] + redB[3];

    float inv = 1.0f / sum;
    for (int j = t; j < L; j += 256) {
        float a = buf[j] * inv;
        row[j] = a;
        rowh[j] = f2bf(a);
    }
    for (int j = L + t; j < SEQ; j += 256) {
        row[j] = 0.f;
        rowh[j] = 0;
    }
}

// ---------------- launch ----------------
extern "C" void kernel_launch(void* const* d_in, const int* in_sizes, int n_in,
                              void* d_out, int out_size, void* d_ws, size_t ws_size,
                              hipStream_t stream) {
    (void)in_sizes; (void)n_in; (void)out_size; (void)ws_size;

    const float* x    = (const float*)d_in[0];
    const float* Wq   = (const float*)d_in[1];
    const float* bq   = (const float*)d_in[2];
    const float* Wk   = (const float*)d_in[3];
    const float* bk   = (const float*)d_in[4];
    const float* Wv   = (const float*)d_in[5];
    const float* bv   = (const float*)d_in[6];
    const float* curv = (const float*)d_in[7];
    const float* temp = (const float*)d_in[8];
    // d_in[9] = mask: causal triu, recomputed from indices instead.

    float* out   = (float*)d_out;                       // [4][2048][512]
    float* attnF = out + (size_t)NB * SEQ * DIM;        // [4][2048][2048]

    char* ws = (char*)d_ws;
    // layout (bytes):
    //   0        x_bf    8,388,608
    //   8388608  Wcat    1,572,864
    //   9961472  qkv_h  25,165,824   (dead after project/transpose)
    //   35127296 qm      8,388,608
    //   43515904 km      8,388,608
    //   51904512 vT      8,388,608
    //   60293120 qn2        32,768
    //   60325888 kn2        32,768
    //   total 60,358,656
    // attnH (33,554,432) aliases [0, 35127296) — x_bf/Wcat/qkv_h all dead by then.
    u16*   x_bf  = (u16*)(ws + 0);
    u16*   Wcat  = (u16*)(ws + 8388608);
    u16*   qkvh  = (u16*)(ws + 9961472);
    u16*   qm    = (u16*)(ws + 35127296);
    u16*   km    = (u16*)(ws + 43515904);
    u16*   vT    = (u16*)(ws + 51904512);
    float* qn2   = (float*)(ws + 60293120);
    float* kn2   = (float*)(ws + 60325888);
    u16*   attnH = (u16*)(ws + 0);

    // K0: conversions
    int n_x = NB * SEQ * DIM;
    cvt_bf16_kernel<<<(n_x + 255) / 256, 256, 0, stream>>>(x, x_bf, n_x);
    int n_w = DIM * DIM;
    cvt_bf16_kernel<<<(n_w + 255) / 256, 256, 0, stream>>>(Wq, Wcat, n_w);
    cvt_bf16_kernel<<<(n_w + 255) / 256, 256, 0, stream>>>(Wk, Wcat + n_w, n_w);
    cvt_bf16_kernel<<<(n_w + 255) / 256, 256, 0, stream>>>(Wv, Wcat + 2 * n_w, n_w);

    // K1: QKV GEMM  M=8192 N=1536 K=512 -> qkv_h bf16 (+bias)
    {
        dim3 g(1536 / 128, 8192 / 128, 1);
        gemm_nt_kernel<0><<<g, 256, 0, stream>>>(
            x_bf, 512, 0, Wcat, 512, 0, (void*)qkvh, 1536, 0, 512,
            bq, bk, bv, nullptr, nullptr, curv, temp);
    }

    // K2: projection (qm/km + qn2/kn2)
    project_kernel<<<NB * SEQ, 256, 0, stream>>>(qkvh, qm, km, qn2, kn2, curv);

    // K2v: transpose v -> vT
    {
        dim3 g(SEQ / 32, DIM / 32, NB), blk(32, 8);
        transpose_v_kernel<<<g, blk, 0, stream>>>(qkvh, vT);
    }

    // K3: scores GEMM + distance epilogue (raw scores into d_out attn region)
    {
        dim3 g(SEQ / 128, SEQ / 128, NB);
        gemm_nt_kernel<1><<<g, 256, 0, stream>>>(
            qm, 512, (long long)SEQ * DIM, km, 512, (long long)SEQ * DIM,
            (void*)attnF, SEQ, (long long)SEQ * SEQ, 512,
            nullptr, nullptr, nullptr, qn2, kn2, curv, temp);
    }

    // K4: softmax (in-place fp32 + bf16 copy)
    softmax_kernel<<<dim3(SEQ, NB), 256, 0, stream>>>(attnF, attnH);

    // K5: PV GEMM  M=2048 N=512 K=2048 (causal K-cap)
    {
        dim3 g(DIM / 128, SEQ / 128, NB);
        gemm_nt_kernel<2><<<g, 256, 0, stream>>>(
            attnH, SEQ, (long long)SEQ * SEQ, vT, SEQ, (long long)DIM * SEQ,
            (void*)out, DIM, (long long)SEQ * DIM, SEQ,
            nullptr, nullptr, nullptr, nullptr, nullptr, curv, temp);
    }
}

// Round 2
// 265.900 us; speedup vs baseline: 1.1789x; 1.1789x over previous
//
#include <hip/hip_runtime.h>
#include <hip/hip_bf16.h>
#include <math.h>

typedef unsigned short u16;
typedef float float4e __attribute__((ext_vector_type(4)));
typedef short short8 __attribute__((ext_vector_type(8)));

#define SEQ 2048
#define DIM 512
#define NB  4

__device__ __forceinline__ float bf2f(u16 h) {
    return __uint_as_float(((unsigned)h) << 16);
}
__device__ __forceinline__ u16 f2bf(float f) {
    __hip_bfloat16 h = __float2bfloat16(f);
    return *reinterpret_cast<u16*>(&h);
}
__device__ __forceinline__ float curv_of(float raw) {
    return -2.0f + 2.0f * (tanhf(raw) + 1.0f);   // bounds (-2,2)
}
// async global->LDS, 16B per lane; lds base must be wave-uniform (lane lands at base+lane*16)
__device__ __forceinline__ void gl_lds16(const u16* g, u16* lds) {
    __builtin_amdgcn_global_load_lds(
        (const __attribute__((address_space(1))) unsigned int*)g,
        (__attribute__((address_space(3))) unsigned int*)lds, 16, 0, 0);
}

// ---------------- fused conversions + l zeroing ----------------
__global__ __launch_bounds__(256) void cvt_all_kernel(
    const float* __restrict__ x, const float* __restrict__ Wq,
    const float* __restrict__ Wk, const float* __restrict__ Wv,
    u16* __restrict__ x_bf, u16* __restrict__ Wcat, float* __restrict__ lsum)
{
    int i = blockIdx.x * 256 + threadIdx.x;
    const int n_x = NB * SEQ * DIM, n_w = DIM * DIM;
    if (i < NB * SEQ) lsum[i] = 0.f;
    if (i < n_x) {
        x_bf[i] = f2bf(x[i]);
    } else if (i < n_x + 3 * n_w) {
        int j = i - n_x;
        const float* W = (j < n_w) ? Wq : (j < 2 * n_w ? Wk : Wv);
        int off = j % n_w;
        Wcat[j] = f2bf(W[off]);
    }
}

// ---------------- QKV GEMM 128x128, BK=32, global_load_lds staging ----------------
__global__ __launch_bounds__(256) void qkv_gemm_kernel(
    const u16* __restrict__ A,    // x_bf [8192][512]
    const u16* __restrict__ Bt,   // Wcat [1536][512]
    u16* __restrict__ C,          // qkvh [8192][1536]
    const float* __restrict__ bq, const float* __restrict__ bk, const float* __restrict__ bv)
{
    int bn = blockIdx.x, bm = blockIdx.y;
    __shared__ __align__(16) u16 As[128 * 32];
    __shared__ __align__(16) u16 Bs[128 * 32];

    int t = threadIdx.x, wave = t >> 6, lane = t & 63;
    int wm = wave >> 1, wn = wave & 1;
    int lrow = lane & 15, quad = lane >> 4;
    int lr4 = lane >> 2, lch = lane & 3;

    float4e acc[4][4];
#pragma unroll
    for (int i = 0; i < 4; i++)
#pragma unroll
        for (int j = 0; j < 4; j++) acc[i][j] = (float4e){0.f, 0.f, 0.f, 0.f};

    for (int kt = 0; kt < 16; ++kt) {
        int k0 = kt << 5;
        __syncthreads();
#pragma unroll
        for (int h = 0; h < 2; ++h) {
            int q = wave + h * 4;          // 8 chunks of 16 rows
            int row = q * 16 + lr4;
            gl_lds16(A  + (size_t)(bm * 128 + row) * 512 + k0 + lch * 8, &As[q * 512]);
            gl_lds16(Bt + (size_t)(bn * 128 + row) * 512 + k0 + lch * 8, &Bs[q * 512]);
        }
        __syncthreads();

        short8 af[4], bfr[4];
#pragma unroll
        for (int im = 0; im < 4; im++)
            af[im] = *(const short8*)&As[(wm * 64 + im * 16 + lrow) * 32 + quad * 8];
#pragma unroll
        for (int in = 0; in < 4; in++)
            bfr[in] = *(const short8*)&Bs[(wn * 64 + in * 16 + lrow) * 32 + quad * 8];
#pragma unroll
        for (int im = 0; im < 4; im++)
#pragma unroll
            for (int in = 0; in < 4; in++)
                acc[im][in] = __builtin_amdgcn_mfma_f32_16x16x32_bf16(af[im], bfr[in], acc[im][in], 0, 0, 0);
    }

#pragma unroll
    for (int im = 0; im < 4; im++)
#pragma unroll
        for (int in = 0; in < 4; in++)
#pragma unroll
            for (int r = 0; r < 4; r++) {
                int i = bm * 128 + wm * 64 + im * 16 + quad * 4 + r;
                int j = bn * 128 + wn * 64 + in * 16 + lrow;
                float bias = (j < 512) ? bq[j] : (j < 1024 ? bk[j - 512] : bv[j - 1024]);
                C[(size_t)i * 1536 + j] = f2bf(acc[im][in][r] + bias);
            }
}

// ---------------- projection ----------------
__global__ __launch_bounds__(256) void project_kernel(
    const u16* __restrict__ qkvh,
    u16* __restrict__ qm, u16* __restrict__ km,
    float* __restrict__ qn2, float* __restrict__ kn2,
    const float* __restrict__ curvp)
{
    int r = blockIdx.x;
    int t = threadIdx.x;
    float kv = curv_of(curvp[0]);
    float absk = fabsf(kv);
    float sk = sqrtf(fmaxf(absk, 1e-5f));

    const u16* qrow = qkvh + (size_t)r * 1536;
    const u16* krow = qrow + 512;
    float q0 = bf2f(qrow[t]), q1 = bf2f(qrow[t + 256]);
    float k0 = bf2f(krow[t]), k1 = bf2f(krow[t + 256]);

    float sq = q0 * q0 + q1 * q1;
    float s2 = k0 * k0 + k1 * k1;
#pragma unroll
    for (int off = 32; off > 0; off >>= 1) {
        sq += __shfl_down(sq, off);
        s2 += __shfl_down(s2, off);
    }
    __shared__ float rq[4], rk[4];
    int wave = t >> 6, lane = t & 63;
    if (lane == 0) { rq[wave] = sq; rk[wave] = s2; }
    __syncthreads();
    float n2q = rq[0] + rq[1] + rq[2] + rq[3];
    float n2k = rk[0] + rk[1] + rk[2] + rk[3];

    float sclq, sclk;
    {
        float nq = sqrtf(n2q + 1e-12f);
        float nk = sqrtf(n2k + 1e-12f);
        if (absk < 0.01f) { sclq = 1.f; sclk = 1.f; }
        else if (kv < 0.f) {
            float mx = (1.0f - 1e-3f) / sk;
            sclq = fminf(1.f, mx / nq);
            sclk = fminf(1.f, mx / nk);
        } else {
            sclq = 1.f / (nq * sk);
            sclk = 1.f / (nk * sk);
        }
    }
    if (t == 0) {
        qn2[r] = n2q * sclq * sclq;
        kn2[r] = n2k * sclk * sclk;
    }
    u16* qo = qm + (size_t)r * 512;
    u16* ko = km + (size_t)r * 512;
    qo[t]       = f2bf(q0 * sclq);
    qo[t + 256] = f2bf(q1 * sclq);
    ko[t]       = f2bf(k0 * sclk);
    ko[t + 256] = f2bf(k1 * sclk);
}

// ---------------- transpose v ----------------
__global__ __launch_bounds__(256) void transpose_v_kernel(
    const u16* __restrict__ qkvh, u16* __restrict__ vT)
{
    __shared__ u16 tile[32][33];
    int b = blockIdx.z;
    int s0 = blockIdx.x * 32, d0 = blockIdx.y * 32;
    int tx = threadIdx.x, ty = threadIdx.y;
#pragma unroll
    for (int r = 0; r < 4; r++) {
        int s = s0 + ty + r * 8;
        tile[ty + r * 8][tx] = qkvh[(size_t)(b * SEQ + s) * 1536 + 1024 + d0 + tx];
    }
    __syncthreads();
#pragma unroll
    for (int r = 0; r < 4; r++) {
        int d = d0 + ty + r * 8;
        int s = s0 + tx;
        vT[((size_t)b * DIM + d) * SEQ + s] = tile[tx][ty + r * 8];
    }
}

// ---------------- scores 64x64 + dist + exp epilogue + row-sum atomics ----------------
__global__ __launch_bounds__(256) void scores_kernel(
    const u16* __restrict__ qm, const u16* __restrict__ km,
    const float* __restrict__ qn2v, const float* __restrict__ kn2v,
    float* __restrict__ attnF, u16* __restrict__ attnH, float* __restrict__ lsum,
    const float* __restrict__ curvp, const float* __restrict__ tempp)
{
    int bn = blockIdx.x, bm = blockIdx.y, b = blockIdx.z;
    if (bn > bm) return;   // causal tile skip

    __shared__ __align__(16) u16 As[64 * 32];
    __shared__ __align__(16) u16 Bs[64 * 32];

    int t = threadIdx.x, wave = t >> 6, lane = t & 63;
    int wr = wave >> 1, wc = wave & 1;
    int lrow = lane & 15, quad = lane >> 4;
    int lr4 = lane >> 2, lch = lane & 3;

    const u16* Ab = qm + (size_t)b * SEQ * DIM;
    const u16* Bb = km + (size_t)b * SEQ * DIM;

    float4e acc[2][2];
#pragma unroll
    for (int i = 0; i < 2; i++)
#pragma unroll
        for (int j = 0; j < 2; j++) acc[i][j] = (float4e){0.f, 0.f, 0.f, 0.f};

    for (int kt = 0; kt < 16; ++kt) {
        int k0 = kt << 5;
        __syncthreads();
        int row = wave * 16 + lr4;
        gl_lds16(Ab + (size_t)(bm * 64 + row) * 512 + k0 + lch * 8, &As[wave * 512]);
        gl_lds16(Bb + (size_t)(bn * 64 + row) * 512 + k0 + lch * 8, &Bs[wave * 512]);
        __syncthreads();

        short8 af[2], bfr[2];
#pragma unroll
        for (int im = 0; im < 2; im++)
            af[im] = *(const short8*)&As[(wr * 32 + im * 16 + lrow) * 32 + quad * 8];
#pragma unroll
        for (int in = 0; in < 2; in++)
            bfr[in] = *(const short8*)&Bs[(wc * 32 + in * 16 + lrow) * 32 + quad * 8];
#pragma unroll
        for (int im = 0; im < 2; im++)
#pragma unroll
            for (int in = 0; in < 2; in++)
                acc[im][in] = __builtin_amdgcn_mfma_f32_16x16x32_bf16(af[im], bfr[in], acc[im][in], 0, 0, 0);
    }

    float kv = curv_of(curvp[0]);
    float absk = fabsf(kv);
    float sk = sqrtf(fmaxf(absk, 1e-5f));
    float invT = 1.0f / (tempp[0] + 1e-8f);

    float* attF = attnF + (size_t)b * SEQ * SEQ;
    u16*   attH = attnH + (size_t)b * SEQ * SEQ;

    float psum[2][4];
#pragma unroll
    for (int im = 0; im < 2; im++)
#pragma unroll
        for (int r = 0; r < 4; r++) psum[im][r] = 0.f;

#pragma unroll
    for (int im = 0; im < 2; im++) {
#pragma unroll
        for (int r = 0; r < 4; r++) {
            int gi = bm * 64 + wr * 32 + im * 16 + quad * 4 + r;
            float qn = qn2v[b * SEQ + gi];
#pragma unroll
            for (int in = 0; in < 2; in++) {
                int gj = bn * 64 + wc * 32 + in * 16 + lrow;
                float kn = kn2v[b * SEQ + gj];
                float dot = acc[im][in][r];
                float diff2 = fmaxf(qn + kn - 2.f * dot, 0.f);
                float dist;
                if (absk < 0.01f) {
                    dist = sqrtf(diff2 + 1e-12f);
                } else if (kv < 0.f) {
                    float denom = fmaxf((1.f - absk * qn) * (1.f - absk * kn), 1e-5f);
                    float arg = fmaxf(1.f + 2.f * absk * diff2 / denom, 1.f + 1e-7f);
                    dist = acoshf(arg) / sk;
                } else {
                    float c = fminf(fmaxf(absk * dot, -1.f + 1e-7f), 1.f - 1e-7f);
                    dist = acosf(c) / sk;
                }
                float s = -dist * invT;
                float e = (gj <= gi) ? __expf(s) : 0.f;   // scores<=0 -> no max-shift needed
                attF[(size_t)gi * SEQ + gj] = e;
                attH[(size_t)gi * SEQ + gj] = f2bf(e);
                psum[im][r] += e;
            }
        }
    }

    // reduce psum across the 16 lanes of each quad-group, then one atomic per row
#pragma unroll
    for (int im = 0; im < 2; im++)
#pragma unroll
        for (int r = 0; r < 4; r++) {
            float v = psum[im][r];
            v += __shfl_xor(v, 1);
            v += __shfl_xor(v, 2);
            v += __shfl_xor(v, 4);
            v += __shfl_xor(v, 8);
            if (lrow == 0) {
                int gi = bm * 64 + wr * 32 + im * 16 + quad * 4 + r;
                atomicAdd(&lsum[b * SEQ + gi], v);
            }
        }
}

// ---------------- PV 64x64, causal K-cap, 1/l epilogue ----------------
__global__ __launch_bounds__(256) void pv_kernel(
    const u16* __restrict__ attnH,   // [b][2048][2048] bf16 unnormalized
    const u16* __restrict__ vT,      // [b][512][2048]
    const float* __restrict__ lsum,
    float* __restrict__ out)         // [b][2048][512]
{
    int bn = blockIdx.x, bm = blockIdx.y, b = blockIdx.z;

    __shared__ __align__(16) u16 As[64 * 32];
    __shared__ __align__(16) u16 Bs[64 * 32];

    int t = threadIdx.x, wave = t >> 6, lane = t & 63;
    int wr = wave >> 1, wc = wave & 1;
    int lrow = lane & 15, quad = lane >> 4;
    int lr4 = lane >> 2, lch = lane & 3;

    const u16* Ab = attnH + (size_t)b * SEQ * SEQ;
    const u16* Bb = vT + (size_t)b * DIM * SEQ;

    float4e acc[2][2];
#pragma unroll
    for (int i = 0; i < 2; i++)
#pragma unroll
        for (int j = 0; j < 2; j++) acc[i][j] = (float4e){0.f, 0.f, 0.f, 0.f};

    int kIters = (bm + 1) * 2;   // rows bm*64.. need j < (bm+1)*64
    for (int kt = 0; kt < kIters; ++kt) {
        int k0 = kt << 5;
        __syncthreads();
        int row = wave * 16 + lr4;
        gl_lds16(Ab + (size_t)(bm * 64 + row) * SEQ + k0 + lch * 8, &As[wave * 512]);
        gl_lds16(Bb + (size_t)(bn * 64 + row) * SEQ + k0 + lch * 8, &Bs[wave * 512]);
        __syncthreads();

        short8 af[2], bfr[2];
#pragma unroll
        for (int im = 0; im < 2; im++)
            af[im] = *(const short8*)&As[(wr * 32 + im * 16 + lrow) * 32 + quad * 8];
#pragma unroll
        for (int in = 0; in < 2; in++)
            bfr[in] = *(const short8*)&Bs[(wc * 32 + in * 16 + lrow) * 32 + quad * 8];
#pragma unroll
        for (int im = 0; im < 2; im++)
#pragma unroll
            for (int in = 0; in < 2; in++)
                acc[im][in] = __builtin_amdgcn_mfma_f32_16x16x32_bf16(af[im], bfr[in], acc[im][in], 0, 0, 0);
    }

#pragma unroll
    for (int im = 0; im < 2; im++)
#pragma unroll
        for (int r = 0; r < 4; r++) {
            int gi = bm * 64 + wr * 32 + im * 16 + quad * 4 + r;
            float invl = 1.0f / lsum[b * SEQ + gi];
#pragma unroll
            for (int in = 0; in < 2; in++) {
                int gd = bn * 64 + wc * 32 + in * 16 + lrow;
                out[((size_t)b * SEQ + gi) * DIM + gd] = acc[im][in][r] * invl;
            }
        }
}

// ---------------- normalize attention in d_out (and zero upper-tri) ----------------
__global__ __launch_bounds__(256) void norm_attn_kernel(
    float* __restrict__ attnF, const float* __restrict__ lsum)
{
    int i = blockIdx.x, b = blockIdx.y, t = threadIdx.x;
    float inv = 1.0f / lsum[b * SEQ + i];
    float4* row = (float4*)(attnF + ((size_t)b * SEQ + i) * SEQ);
#pragma unroll
    for (int c = t; c < SEQ / 4; c += 256) {
        int j0 = c * 4;
        float4 v = row[c];
        v.x = (j0     <= i) ? v.x * inv : 0.f;
        v.y = (j0 + 1 <= i) ? v.y * inv : 0.f;
        v.z = (j0 + 2 <= i) ? v.z * inv : 0.f;
        v.w = (j0 + 3 <= i) ? v.w * inv : 0.f;
        row[c] = v;
    }
}

// ---------------- launch ----------------
extern "C" void kernel_launch(void* const* d_in, const int* in_sizes, int n_in,
                              void* d_out, int out_size, void* d_ws, size_t ws_size,
                              hipStream_t stream) {
    (void)in_sizes; (void)n_in; (void)out_size; (void)ws_size;

    const float* x    = (const float*)d_in[0];
    const float* Wq   = (const float*)d_in[1];
    const float* bq   = (const float*)d_in[2];
    const float* Wk   = (const float*)d_in[3];
    const float* bk   = (const float*)d_in[4];
    const float* Wv   = (const float*)d_in[5];
    const float* bv   = (const float*)d_in[6];
    const float* curv = (const float*)d_in[7];
    const float* temp = (const float*)d_in[8];

    float* out   = (float*)d_out;                       // [4][2048][512]
    float* attnF = out + (size_t)NB * SEQ * DIM;        // [4][2048][2048]

    char* ws = (char*)d_ws;
    // layout (bytes):
    //   0        x_bf    8,388,608   (dead after QKV)
    //   8388608  Wcat    1,572,864   (dead after QKV)
    //   9961472  qkvh   25,165,824   (dead after project/transpose)
    //   35127296 qm      8,388,608
    //   43515904 km      8,388,608
    //   51904512 vT      8,388,608
    //   60293120 qn2        32,768
    //   60325888 kn2        32,768
    //   60358656 lsum       32,768
    // attnH (33,554,432) aliases [0, 33554432) — x_bf/Wcat/qkvh all dead by then.
    u16*   x_bf  = (u16*)(ws + 0);
    u16*   Wcat  = (u16*)(ws + 8388608);
    u16*   qkvh  = (u16*)(ws + 9961472);
    u16*   qm    = (u16*)(ws + 35127296);
    u16*   km    = (u16*)(ws + 43515904);
    u16*   vT    = (u16*)(ws + 51904512);
    float* qn2   = (float*)(ws + 60293120);
    float* kn2   = (float*)(ws + 60325888);
    float* lsum  = (float*)(ws + 60358656);
    u16*   attnH = (u16*)(ws + 0);

    // K0: conversions + lsum zero (single launch)
    {
        int n_tot = NB * SEQ * DIM + 3 * DIM * DIM;
        cvt_all_kernel<<<(n_tot + 255) / 256, 256, 0, stream>>>(x, Wq, Wk, Wv, x_bf, Wcat, lsum);
    }

    // K1: QKV GEMM
    {
        dim3 g(1536 / 128, 8192 / 128, 1);
        qkv_gemm_kernel<<<g, 256, 0, stream>>>(x_bf, Wcat, qkvh, bq, bk, bv);
    }

    // K2: projection
    project_kernel<<<NB * SEQ, 256, 0, stream>>>(qkvh, qm, km, qn2, kn2, curv);

    // K2v: transpose v
    {
        dim3 g(SEQ / 32, DIM / 32, NB), blk(32, 8);
        transpose_v_kernel<<<g, blk, 0, stream>>>(qkvh, vT);
    }

    // K3: scores + dist + exp (unnormalized) + row sums
    {
        dim3 g(SEQ / 64, SEQ / 64, NB);
        scores_kernel<<<g, 256, 0, stream>>>(qm, km, qn2, kn2, attnF, attnH, lsum, curv, temp);
    }

    // K4: PV with 1/l scaling
    {
        dim3 g(DIM / 64, SEQ / 64, NB);
        pv_kernel<<<g, 256, 0, stream>>>(attnH, vT, lsum, out);
    }

    // K5: normalize attention output
    norm_attn_kernel<<<dim3(SEQ, NB), 256, 0, stream>>>(attnF, lsum);
}

// Round 3
// 250.961 us; speedup vs baseline: 1.2491x; 1.0595x over previous
//
#include <hip/hip_runtime.h>
#include <hip/hip_bf16.h>
#include <math.h>

typedef unsigned short u16;
typedef float float4e __attribute__((ext_vector_type(4)));
typedef short short8 __attribute__((ext_vector_type(8)));
typedef unsigned short ushort8 __attribute__((ext_vector_type(8)));

#define SEQ 2048
#define DIM 512
#define NB  4

__device__ __forceinline__ float bf2f(u16 h) {
    return __uint_as_float(((unsigned)h) << 16);
}
__device__ __forceinline__ u16 f2bf(float f) {
    __hip_bfloat16 h = __float2bfloat16(f);
    return *reinterpret_cast<u16*>(&h);
}
__device__ __forceinline__ float curv_of(float raw) {
    return -2.0f + 2.0f * (tanhf(raw) + 1.0f);   // bounds (-2,2)
}
// async global->LDS, 16B per lane; lds base wave-uniform (lane lands at base+lane*16)
__device__ __forceinline__ void gl_lds16(const u16* g, u16* lds) {
    __builtin_amdgcn_global_load_lds(
        (const __attribute__((address_space(1))) unsigned int*)g,
        (__attribute__((address_space(3))) unsigned int*)lds, 16, 0, 0);
}

// ---------------- fused conversions + lsum zeroing ----------------
__global__ __launch_bounds__(256) void cvt_all_kernel(
    const float* __restrict__ x, const float* __restrict__ Wq,
    const float* __restrict__ Wk, const float* __restrict__ Wv,
    u16* __restrict__ x_bf, u16* __restrict__ Wcat, float* __restrict__ lsum)
{
    int i = blockIdx.x * 256 + threadIdx.x;
    const int n_x = NB * SEQ * DIM, n_w = DIM * DIM;
    if (i < NB * SEQ) lsum[i] = 0.f;
    if (i < n_x) {
        x_bf[i] = f2bf(x[i]);
    } else if (i < n_x + 3 * n_w) {
        int j = i - n_x;
        const float* W = (j < n_w) ? Wq : (j < 2 * n_w ? Wk : Wv);
        int off = j % n_w;
        Wcat[j] = f2bf(W[off]);
    }
}

// =====================================================================
// Unified 64x64-tile GEMM, BK=128 (4 staging iters for K=512), XOR-swizzled
// LDS (conflict-free ds_read_b128 under global_load_lds's lane-linear dest).
// MODE 0: QKV   C=bf16 [8192][1536], +bias epilogue
// MODE 1: scores C=attnH bf16, dist+exp epilogue + lsum atomics; causal skip;
//                zero-fills superdiagonal tile (bm even) needed by PV's BK=128
// MODE 2: PV    C=out fp32, 1/lsum epilogue, kIters=(bm+2)>>1
// =====================================================================
template<int MODE>
__global__ __launch_bounds__(256) void gemm64_kernel(
    const u16* __restrict__ A, int lda, long long sA,
    const u16* __restrict__ Bt, int ldb, long long sB,
    void* __restrict__ Cv, int ldc, long long sC,
    float* __restrict__ lsum,
    const float* __restrict__ bq, const float* __restrict__ bk, const float* __restrict__ bv,
    const float* __restrict__ qn2v, const float* __restrict__ kn2v,
    const float* __restrict__ curvp, const float* __restrict__ tempp)
{
    int bn = blockIdx.x, bm = blockIdx.y, b = blockIdx.z;
    int t = threadIdx.x, wave = t >> 6, lane = t & 63;

    if (MODE == 1) {
        if (bn > bm) {
            // PV (BK=128) reads tile-column bm+1 when bm is even: zero-fill it.
            if (bn == bm + 1 && !(bm & 1)) {
                u16* Cb = (u16*)Cv + (size_t)b * sC;
                int r = t >> 2, seg = t & 3;
                int4 z = {0, 0, 0, 0};
                int4* p = (int4*)&Cb[(size_t)(bm * 64 + r) * ldc + bn * 64 + seg * 16];
                p[0] = z; p[1] = z;
            }
            return;
        }
    }

    __shared__ __align__(16) u16 As[64 * 128];
    __shared__ __align__(16) u16 Bs[64 * 128];

    int wr = wave >> 1, wc = wave & 1;
    int lrow = lane & 15, quad = lane >> 4;
    int rl = lane >> 4, cs = lane & 15;

    const u16* Ab = A + (size_t)b * sA + (size_t)(bm * 64) * lda;
    const u16* Bb = Bt + (size_t)b * sB + (size_t)(bn * 64) * ldb;

    float4e acc[2][2];
#pragma unroll
    for (int i = 0; i < 2; i++)
#pragma unroll
        for (int j = 0; j < 2; j++) acc[i][j] = (float4e){0.f, 0.f, 0.f, 0.f};

    int kIters = (MODE == 2) ? ((bm + 2) >> 1) : 4;

    for (int kt = 0; kt < kIters; ++kt) {
        int k0 = kt << 7;
        __syncthreads();
        // stage 64 rows x 128 cols per tile; each wave: 4 calls x 4 rows.
        // LDS layout: row-major, but 16B chunk c of row r lands at slot (c ^ (r&15)).
#pragma unroll
        for (int h = 0; h < 4; ++h) {
            int row = wave * 16 + h * 4 + rl;
            int c = cs ^ (row & 15);
            gl_lds16(Ab + (size_t)row * lda + k0 + c * 8, &As[(wave * 16 + h * 4) * 128]);
            gl_lds16(Bb + (size_t)row * ldb + k0 + c * 8, &Bs[(wave * 16 + h * 4) * 128]);
        }
        __syncthreads();
#pragma unroll
        for (int s = 0; s < 4; ++s) {
            short8 af[2], bfr[2];
#pragma unroll
            for (int im = 0; im < 2; im++) {
                int row = wr * 32 + im * 16 + lrow;
                af[im] = *(const short8*)&As[(row * 16 + ((s * 4 + quad) ^ (row & 15))) * 8];
            }
#pragma unroll
            for (int in = 0; in < 2; in++) {
                int row = wc * 32 + in * 16 + lrow;
                bfr[in] = *(const short8*)&Bs[(row * 16 + ((s * 4 + quad) ^ (row & 15))) * 8];
            }
#pragma unroll
            for (int im = 0; im < 2; im++)
#pragma unroll
                for (int in = 0; in < 2; in++)
                    acc[im][in] = __builtin_amdgcn_mfma_f32_16x16x32_bf16(af[im], bfr[in], acc[im][in], 0, 0, 0);
        }
    }

    // ---------------- epilogues ----------------
    if (MODE == 0) {
        u16* Cb = (u16*)Cv;
#pragma unroll
        for (int im = 0; im < 2; im++)
#pragma unroll
            for (int in = 0; in < 2; in++)
#pragma unroll
                for (int r = 0; r < 4; r++) {
                    int gi = bm * 64 + wr * 32 + im * 16 + quad * 4 + r;
                    int gj = bn * 64 + wc * 32 + in * 16 + lrow;
                    float bias = (gj < 512) ? bq[gj] : (gj < 1024 ? bk[gj - 512] : bv[gj - 1024]);
                    Cb[(size_t)gi * ldc + gj] = f2bf(acc[im][in][r] + bias);
                }
    } else if (MODE == 1) {
        float kv = curv_of(curvp[0]);
        float absk = fabsf(kv);
        float sk = sqrtf(fmaxf(absk, 1e-5f));
        float invT = 1.0f / (tempp[0] + 1e-8f);
        u16* Cb = (u16*)Cv + (size_t)b * sC;

        float psum[2][4];
#pragma unroll
        for (int im = 0; im < 2; im++)
#pragma unroll
            for (int r = 0; r < 4; r++) psum[im][r] = 0.f;

#pragma unroll
        for (int im = 0; im < 2; im++) {
#pragma unroll
            for (int r = 0; r < 4; r++) {
                int gi = bm * 64 + wr * 32 + im * 16 + quad * 4 + r;
                float qn = qn2v[b * SEQ + gi];
#pragma unroll
                for (int in = 0; in < 2; in++) {
                    int gj = bn * 64 + wc * 32 + in * 16 + lrow;
                    float kn = kn2v[b * SEQ + gj];
                    float dot = acc[im][in][r];
                    float diff2 = fmaxf(qn + kn - 2.f * dot, 0.f);
                    float dist;
                    if (absk < 0.01f) {
                        dist = sqrtf(diff2 + 1e-12f);
                    } else if (kv < 0.f) {
                        float denom = fmaxf((1.f - absk * qn) * (1.f - absk * kn), 1e-5f);
                        float arg = fmaxf(1.f + 2.f * absk * diff2 / denom, 1.f + 1e-7f);
                        dist = acoshf(arg) / sk;
                    } else {
                        float c = fminf(fmaxf(absk * dot, -1.f + 1e-7f), 1.f - 1e-7f);
                        dist = acosf(c) / sk;
                    }
                    float s = -dist * invT;
                    float e = (gj <= gi) ? __expf(s) : 0.f;   // scores<=0 -> no max shift
                    Cb[(size_t)gi * ldc + gj] = f2bf(e);
                    psum[im][r] += e;
                }
            }
        }
#pragma unroll
        for (int im = 0; im < 2; im++)
#pragma unroll
            for (int r = 0; r < 4; r++) {
                float v = psum[im][r];
                v += __shfl_xor(v, 1);
                v += __shfl_xor(v, 2);
                v += __shfl_xor(v, 4);
                v += __shfl_xor(v, 8);
                if (lrow == 0) {
                    int gi = bm * 64 + wr * 32 + im * 16 + quad * 4 + r;
                    atomicAdd(&lsum[b * SEQ + gi], v);
                }
            }
    } else {
        float* Cb = (float*)Cv + (size_t)b * sC;
#pragma unroll
        for (int im = 0; im < 2; im++)
#pragma unroll
            for (int r = 0; r < 4; r++) {
                int gi = bm * 64 + wr * 32 + im * 16 + quad * 4 + r;
                float invl = 1.0f / lsum[b * SEQ + gi];
#pragma unroll
                for (int in = 0; in < 2; in++) {
                    int gd = bn * 64 + wc * 32 + in * 16 + lrow;
                    Cb[(size_t)gi * ldc + gd] = acc[im][in][r] * invl;
                }
            }
    }
}

// ---------------- projection ----------------
__global__ __launch_bounds__(256) void project_kernel(
    const u16* __restrict__ qkvh,
    u16* __restrict__ qm, u16* __restrict__ km,
    float* __restrict__ qn2, float* __restrict__ kn2,
    const float* __restrict__ curvp)
{
    int r = blockIdx.x;
    int t = threadIdx.x;
    float kv = curv_of(curvp[0]);
    float absk = fabsf(kv);
    float sk = sqrtf(fmaxf(absk, 1e-5f));

    const u16* qrow = qkvh + (size_t)r * 1536;
    const u16* krow = qrow + 512;
    float q0 = bf2f(qrow[t]), q1 = bf2f(qrow[t + 256]);
    float k0 = bf2f(krow[t]), k1 = bf2f(krow[t + 256]);

    float sq = q0 * q0 + q1 * q1;
    float s2 = k0 * k0 + k1 * k1;
#pragma unroll
    for (int off = 32; off > 0; off >>= 1) {
        sq += __shfl_down(sq, off);
        s2 += __shfl_down(s2, off);
    }
    __shared__ float rq[4], rk[4];
    int wave = t >> 6, lane = t & 63;
    if (lane == 0) { rq[wave] = sq; rk[wave] = s2; }
    __syncthreads();
    float n2q = rq[0] + rq[1] + rq[2] + rq[3];
    float n2k = rk[0] + rk[1] + rk[2] + rk[3];

    float sclq, sclk;
    {
        float nq = sqrtf(n2q + 1e-12f);
        float nk = sqrtf(n2k + 1e-12f);
        if (absk < 0.01f) { sclq = 1.f; sclk = 1.f; }
        else if (kv < 0.f) {
            float mx = (1.0f - 1e-3f) / sk;
            sclq = fminf(1.f, mx / nq);
            sclk = fminf(1.f, mx / nk);
        } else {
            sclq = 1.f / (nq * sk);
            sclk = 1.f / (nk * sk);
        }
    }
    if (t == 0) {
        qn2[r] = n2q * sclq * sclq;
        kn2[r] = n2k * sclk * sclk;
    }
    u16* qo = qm + (size_t)r * 512;
    u16* ko = km + (size_t)r * 512;
    qo[t]       = f2bf(q0 * sclq);
    qo[t + 256] = f2bf(q1 * sclq);
    ko[t]       = f2bf(k0 * sclk);
    ko[t + 256] = f2bf(k1 * sclk);
}

// ---------------- transpose v ----------------
__global__ __launch_bounds__(256) void transpose_v_kernel(
    const u16* __restrict__ qkvh, u16* __restrict__ vT)
{
    __shared__ u16 tile[32][33];
    int b = blockIdx.z;
    int s0 = blockIdx.x * 32, d0 = blockIdx.y * 32;
    int tx = threadIdx.x, ty = threadIdx.y;
#pragma unroll
    for (int r = 0; r < 4; r++) {
        int s = s0 + ty + r * 8;
        tile[ty + r * 8][tx] = qkvh[(size_t)(b * SEQ + s) * 1536 + 1024 + d0 + tx];
    }
    __syncthreads();
#pragma unroll
    for (int r = 0; r < 4; r++) {
        int d = d0 + ty + r * 8;
        int s = s0 + tx;
        vT[((size_t)b * DIM + d) * SEQ + s] = tile[tx][ty + r * 8];
    }
}

// ---------------- normalize: attnH bf16 -> attnF fp32 (zero upper-tri) ----------------
__global__ __launch_bounds__(256) void norm_attn_kernel(
    const u16* __restrict__ attnH, const float* __restrict__ lsum,
    float* __restrict__ attnF)
{
    int i = blockIdx.x, b = blockIdx.y, t = threadIdx.x;
    float inv = 1.0f / lsum[b * SEQ + i];
    const u16* rowh = attnH + ((size_t)b * SEQ + i) * SEQ;
    float* row = attnF + ((size_t)b * SEQ + i) * SEQ;
    int L = i + 1;
    int j0 = t * 8;
    float4 lo, hi;
    if (j0 + 8 <= L) {
        ushort8 h = *(const ushort8*)&rowh[j0];
        lo.x = bf2f(h[0]) * inv; lo.y = bf2f(h[1]) * inv;
        lo.z = bf2f(h[2]) * inv; lo.w = bf2f(h[3]) * inv;
        hi.x = bf2f(h[4]) * inv; hi.y = bf2f(h[5]) * inv;
        hi.z = bf2f(h[6]) * inv; hi.w = bf2f(h[7]) * inv;
    } else {
        float v[8];
#pragma unroll
        for (int e = 0; e < 8; e++)
            v[e] = (j0 + e < L) ? bf2f(rowh[j0 + e]) * inv : 0.f;
        lo = (float4){v[0], v[1], v[2], v[3]};
        hi = (float4){v[4], v[5], v[6], v[7]};
    }
    *(float4*)&row[j0] = lo;
    *(float4*)&row[j0 + 4] = hi;
}

// ---------------- launch ----------------
extern "C" void kernel_launch(void* const* d_in, const int* in_sizes, int n_in,
                              void* d_out, int out_size, void* d_ws, size_t ws_size,
                              hipStream_t stream) {
    (void)in_sizes; (void)n_in; (void)out_size; (void)ws_size;

    const float* x    = (const float*)d_in[0];
    const float* Wq   = (const float*)d_in[1];
    const float* bq   = (const float*)d_in[2];
    const float* Wk   = (const float*)d_in[3];
    const float* bk   = (const float*)d_in[4];
    const float* Wv   = (const float*)d_in[5];
    const float* bv   = (const float*)d_in[6];
    const float* curv = (const float*)d_in[7];
    const float* temp = (const float*)d_in[8];

    float* out   = (float*)d_out;                       // [4][2048][512]
    float* attnF = out + (size_t)NB * SEQ * DIM;        // [4][2048][2048]

    char* ws = (char*)d_ws;
    // layout (bytes):
    //   0        x_bf    8,388,608   (dead after QKV)
    //   8388608  Wcat    1,572,864   (dead after QKV)
    //   9961472  qkvh   25,165,824   (dead after project/transpose)
    //   35127296 qm      8,388,608
    //   43515904 km      8,388,608
    //   51904512 vT      8,388,608
    //   60293120 qn2        32,768
    //   60325888 kn2        32,768
    //   60358656 lsum       32,768
    // attnH (33,554,432) aliases [0, 33554432) — x_bf/Wcat/qkvh all dead by then.
    u16*   x_bf  = (u16*)(ws + 0);
    u16*   Wcat  = (u16*)(ws + 8388608);
    u16*   qkvh  = (u16*)(ws + 9961472);
    u16*   qm    = (u16*)(ws + 35127296);
    u16*   km    = (u16*)(ws + 43515904);
    u16*   vT    = (u16*)(ws + 51904512);
    float* qn2   = (float*)(ws + 60293120);
    float* kn2   = (float*)(ws + 60325888);
    float* lsum  = (float*)(ws + 60358656);
    u16*   attnH = (u16*)(ws + 0);

    // K0: conversions + lsum zero
    {
        int n_tot = NB * SEQ * DIM + 3 * DIM * DIM;
        cvt_all_kernel<<<(n_tot + 255) / 256, 256, 0, stream>>>(x, Wq, Wk, Wv, x_bf, Wcat, lsum);
    }

    // K1: QKV GEMM  (M=8192, N=1536, K=512)
    gemm64_kernel<0><<<dim3(1536 / 64, 8192 / 64, 1), 256, 0, stream>>>(
        x_bf, 512, 0, Wcat, 512, 0, (void*)qkvh, 1536, 0,
        nullptr, bq, bk, bv, nullptr, nullptr, nullptr, nullptr);

    // K2: projection
    project_kernel<<<NB * SEQ, 256, 0, stream>>>(qkvh, qm, km, qn2, kn2, curv);

    // K2v: transpose v
    {
        dim3 g(SEQ / 32, DIM / 32, NB), blk(32, 8);
        transpose_v_kernel<<<g, blk, 0, stream>>>(qkvh, vT);
    }

    // K3: scores + dist + exp (unnormalized bf16) + row sums
    gemm64_kernel<1><<<dim3(SEQ / 64, SEQ / 64, NB), 256, 0, stream>>>(
        qm, 512, (long long)SEQ * DIM, km, 512, (long long)SEQ * DIM,
        (void*)attnH, SEQ, (long long)SEQ * SEQ,
        lsum, nullptr, nullptr, nullptr, qn2, kn2, curv, temp);

    // K4: PV with 1/l scaling
    gemm64_kernel<2><<<dim3(DIM / 64, SEQ / 64, NB), 256, 0, stream>>>(
        attnH, SEQ, (long long)SEQ * SEQ, vT, SEQ, (long long)DIM * SEQ,
        (void*)out, DIM, (long long)SEQ * DIM,
        lsum, nullptr, nullptr, nullptr, nullptr, nullptr, nullptr, nullptr);

    // K5: attention fp32 output from bf16 + 1/l
    norm_attn_kernel<<<dim3(SEQ, NB), 256, 0, stream>>>(attnH, lsum, attnF);
}

// Round 5
// 239.385 us; speedup vs baseline: 1.3095x; 1.0484x over previous
//
#include <hip/hip_runtime.h>
#include <hip/hip_bf16.h>
#include <math.h>

typedef unsigned short u16;
typedef float float4e __attribute__((ext_vector_type(4)));
typedef short short8 __attribute__((ext_vector_type(8)));
typedef unsigned short ushort8 __attribute__((ext_vector_type(8)));
typedef unsigned short u16x4 __attribute__((ext_vector_type(4)));

#define SEQ 2048
#define DIM 512
#define NB  4

__device__ __forceinline__ float bf2f(u16 h) {
    return __uint_as_float(((unsigned)h) << 16);
}
__device__ __forceinline__ u16 f2bf(float f) {
    __hip_bfloat16 h = __float2bfloat16(f);
    return *reinterpret_cast<u16*>(&h);
}
__device__ __forceinline__ float curv_of(float raw) {
    return -2.0f + 2.0f * (tanhf(raw) + 1.0f);   // bounds (-2,2)
}
// async global->LDS, 16B per lane; lds base wave-uniform (lane lands at base+lane*16)
__device__ __forceinline__ void gl_lds16(const u16* g, u16* lds) {
    __builtin_amdgcn_global_load_lds(
        (const __attribute__((address_space(1))) unsigned int*)g,
        (__attribute__((address_space(3))) unsigned int*)lds, 16, 0, 0);
}

// ---------------- fused conversions + lsum zero + out zero (vectorized x4) ----------------
__global__ __launch_bounds__(256) void cvt_all_kernel(
    const float* __restrict__ x, const float* __restrict__ Wq,
    const float* __restrict__ Wk, const float* __restrict__ Wv,
    u16* __restrict__ x_bf, u16* __restrict__ Wcat, float* __restrict__ lsum,
    float* __restrict__ outz)
{
    const int n_x = NB * SEQ * DIM, n_w = DIM * DIM;
    const int n_out = NB * SEQ * DIM;
    int gid = blockIdx.x * 256 + threadIdx.x;
    if (gid < NB * SEQ) lsum[gid] = 0.f;
    if (gid < n_out / 4) ((float4*)outz)[gid] = (float4){0.f, 0.f, 0.f, 0.f};
    int i4 = gid * 4;
    if (i4 < n_x) {
        float4 v = *(const float4*)&x[i4];
        u16x4 h = {f2bf(v.x), f2bf(v.y), f2bf(v.z), f2bf(v.w)};
        *(u16x4*)&x_bf[i4] = h;
    } else if (i4 < n_x + 3 * n_w) {
        int j = i4 - n_x;
        const float* W = (j < n_w) ? Wq : (j < 2 * n_w ? Wk : Wv);
        int off = j % n_w;
        float4 v = *(const float4*)&W[off];
        u16x4 h = {f2bf(v.x), f2bf(v.y), f2bf(v.z), f2bf(v.w)};
        *(u16x4*)&Wcat[j] = h;
    }
}

// =====================================================================
// Unified 64x64-tile GEMM, BK=64 (16 KB LDS -> 8 blocks/CU), XOR-swizzled
// LDS (conflict-free ds_read_b128 under global_load_lds's lane-linear dest).
// MODE 0: QKV   C=bf16 [8192][1536], +bias; V columns also emit vT[b][d][s]
// MODE 1: scores C=attnH bf16, dist+exp epilogue + lsum atomics; causal skip
// MODE 2: PV    split-K x2, atomicAdd fp32 epilogue with 1/lsum
// =====================================================================
template<int MODE>
__global__ __launch_bounds__(256, 8) void gemm64_kernel(
    const u16* __restrict__ A, int lda, long long sA,
    const u16* __restrict__ Bt, int ldb, long long sB,
    void* __restrict__ Cv, int ldc, long long sC,
    u16* __restrict__ vT,
    float* __restrict__ lsum,
    const float* __restrict__ bq, const float* __restrict__ bk, const float* __restrict__ bv,
    const float* __restrict__ qn2v, const float* __restrict__ kn2v,
    const float* __restrict__ curvp, const float* __restrict__ tempp)
{
    int bx = blockIdx.x, bm = blockIdx.y, b = blockIdx.z;
    int bn = (MODE == 2) ? (bx & 7) : bx;
    int kp = (MODE == 2) ? (bx >> 3) : 0;
    if (MODE == 1 && bn > bm) return;   // causal tile skip (BK=64 aligns: no fill needed)

    __shared__ __align__(16) u16 As[64 * 64];
    __shared__ __align__(16) u16 Bs[64 * 64];

    int t = threadIdx.x, wave = t >> 6, lane = t & 63;
    int wr = wave >> 1, wc = wave & 1;
    int lrow = lane & 15, quad = lane >> 4;
    int srow = lane >> 3, sc = lane & 7;   // staging: 8 rows x 8 chunks per call

    const u16* Ab = A + (size_t)b * sA + (size_t)(bm * 64) * lda;
    const u16* Bb = Bt + (size_t)b * sB + (size_t)(bn * 64) * ldb;

    float4e acc[2][2];
#pragma unroll
    for (int i = 0; i < 2; i++)
#pragma unroll
        for (int j = 0; j < 2; j++) acc[i][j] = (float4e){0.f, 0.f, 0.f, 0.f};

    int ktBeg = (MODE == 2) ? kp : 0;
    int ktEnd = (MODE == 2) ? (bm + 1) : 8;
    int ktStp = (MODE == 2) ? 2 : 1;

    for (int kt = ktBeg; kt < ktEnd; kt += ktStp) {
        int k0 = kt << 6;
        __syncthreads();
        // stage 64x64: per wave 2 calls per array, call q covers rows q*8..q*8+7.
        // 16B chunk sc of row r stored at slot (sc ^ (r&7)) -> conflict-free frag reads.
#pragma unroll
        for (int h = 0; h < 2; ++h) {
            int q = wave * 2 + h;
            int row = q * 8 + srow;
            int c = sc ^ (row & 7);
            gl_lds16(Ab + (size_t)row * lda + k0 + c * 8, &As[q * 512]);
            gl_lds16(Bb + (size_t)row * ldb + k0 + c * 8, &Bs[q * 512]);
        }
        __syncthreads();
#pragma unroll
        for (int s = 0; s < 2; ++s) {
            short8 af[2], bfr[2];
#pragma unroll
            for (int im = 0; im < 2; im++) {
                int R = wr * 32 + im * 16 + lrow;
                af[im] = *(const short8*)&As[R * 64 + (((s * 4 + quad) ^ (R & 7)) * 8)];
            }
#pragma unroll
            for (int in = 0; in < 2; in++) {
                int R = wc * 32 + in * 16 + lrow;
                bfr[in] = *(const short8*)&Bs[R * 64 + (((s * 4 + quad) ^ (R & 7)) * 8)];
            }
#pragma unroll
            for (int im = 0; im < 2; im++)
#pragma unroll
                for (int in = 0; in < 2; in++)
                    acc[im][in] = __builtin_amdgcn_mfma_f32_16x16x32_bf16(af[im], bfr[in], acc[im][in], 0, 0, 0);
        }
    }

    // ---------------- epilogues ----------------
    if (MODE == 0) {
        u16* Cb = (u16*)Cv;
#pragma unroll
        for (int im = 0; im < 2; im++)
#pragma unroll
            for (int in = 0; in < 2; in++) {
                int gi0 = bm * 64 + wr * 32 + im * 16 + quad * 4;
                int gj = bn * 64 + wc * 32 + in * 16 + lrow;
                float bias = (gj < 512) ? bq[gj] : (gj < 1024 ? bk[gj - 512] : bv[gj - 1024]);
                u16x4 pack;
#pragma unroll
                for (int r = 0; r < 4; r++) {
                    u16 hv = f2bf(acc[im][in][r] + bias);
                    Cb[(size_t)(gi0 + r) * ldc + gj] = hv;
                    pack[r] = hv;
                }
                if (gj >= 1024) {   // also emit vT[b][d][s] (4 consecutive s -> 8B store)
                    int bb = gi0 >> 11, s = gi0 & 2047;
                    *(u16x4*)&vT[((size_t)bb * DIM + (gj - 1024)) * SEQ + s] = pack;
                }
            }
    } else if (MODE == 1) {
        float kv = curv_of(curvp[0]);
        float absk = fabsf(kv);
        float sk = sqrtf(fmaxf(absk, 1e-5f));
        float invT = 1.0f / (tempp[0] + 1e-8f);
        u16* Cb = (u16*)Cv + (size_t)b * sC;

        float psum[2][4];
#pragma unroll
        for (int im = 0; im < 2; im++)
#pragma unroll
            for (int r = 0; r < 4; r++) psum[im][r] = 0.f;

#pragma unroll
        for (int im = 0; im < 2; im++) {
#pragma unroll
            for (int r = 0; r < 4; r++) {
                int gi = bm * 64 + wr * 32 + im * 16 + quad * 4 + r;
                float qn = qn2v[b * SEQ + gi];
#pragma unroll
                for (int in = 0; in < 2; in++) {
                    int gj = bn * 64 + wc * 32 + in * 16 + lrow;
                    float kn = kn2v[b * SEQ + gj];
                    float dot = acc[im][in][r];
                    float diff2 = fmaxf(qn + kn - 2.f * dot, 0.f);
                    float dist;
                    if (absk < 0.01f) {
                        dist = sqrtf(diff2 + 1e-12f);
                    } else if (kv < 0.f) {
                        float denom = fmaxf((1.f - absk * qn) * (1.f - absk * kn), 1e-5f);
                        float arg = fmaxf(1.f + 2.f * absk * diff2 / denom, 1.f + 1e-7f);
                        dist = acoshf(arg) / sk;
                    } else {
                        float c = fminf(fmaxf(absk * dot, -1.f + 1e-7f), 1.f - 1e-7f);
                        dist = acosf(c) / sk;
                    }
                    float s = -dist * invT;
                    float e = (gj <= gi) ? __expf(s) : 0.f;   // scores<=0 -> no max shift
                    Cb[(size_t)gi * ldc + gj] = f2bf(e);
                    psum[im][r] += e;
                }
            }
        }
#pragma unroll
        for (int im = 0; im < 2; im++)
#pragma unroll
            for (int r = 0; r < 4; r++) {
                float v = psum[im][r];
                v += __shfl_xor(v, 1);
                v += __shfl_xor(v, 2);
                v += __shfl_xor(v, 4);
                v += __shfl_xor(v, 8);
                if (lrow == 0) {
                    int gi = bm * 64 + wr * 32 + im * 16 + quad * 4 + r;
                    atomicAdd(&lsum[b * SEQ + gi], v);
                }
            }
    } else {
        float* Cb = (float*)Cv + (size_t)b * sC;
#pragma unroll
        for (int im = 0; im < 2; im++)
#pragma unroll
            for (int r = 0; r < 4; r++) {
                int gi = bm * 64 + wr * 32 + im * 16 + quad * 4 + r;
                float invl = 1.0f / lsum[b * SEQ + gi];
#pragma unroll
                for (int in = 0; in < 2; in++) {
                    int gd = bn * 64 + wc * 32 + in * 16 + lrow;
                    atomicAdd(&Cb[(size_t)gi * ldc + gd], acc[im][in][r] * invl);
                }
            }
    }
}

// ---------------- projection: wave-per-row, 16B vector loads/stores ----------------
__global__ __launch_bounds__(256) void project_kernel(
    const u16* __restrict__ qkvh,
    u16* __restrict__ qm, u16* __restrict__ km,
    float* __restrict__ qn2, float* __restrict__ kn2,
    const float* __restrict__ curvp)
{
    int wave = threadIdx.x >> 6, lane = threadIdx.x & 63;
    int r = blockIdx.x * 4 + wave;
    float kv = curv_of(curvp[0]);
    float absk = fabsf(kv);
    float sk = sqrtf(fmaxf(absk, 1e-5f));

    const u16* qrow = qkvh + (size_t)r * 1536;
    ushort8 qh = *(const ushort8*)&qrow[lane * 8];
    ushort8 kh = *(const ushort8*)&qrow[512 + lane * 8];

    float qv[8], kw[8];
    float sq = 0.f, s2 = 0.f;
#pragma unroll
    for (int e = 0; e < 8; e++) {
        qv[e] = bf2f(qh[e]); sq += qv[e] * qv[e];
        kw[e] = bf2f(kh[e]); s2 += kw[e] * kw[e];
    }
#pragma unroll
    for (int off = 1; off < 64; off <<= 1) {
        sq += __shfl_xor(sq, off);
        s2 += __shfl_xor(s2, off);
    }

    float sclq, sclk;
    {
        float nq = sqrtf(sq + 1e-12f);
        float nk = sqrtf(s2 + 1e-12f);
        if (absk < 0.01f) { sclq = 1.f; sclk = 1.f; }
        else if (kv < 0.f) {
            float mx = (1.0f - 1e-3f) / sk;
            sclq = fminf(1.f, mx / nq);
            sclk = fminf(1.f, mx / nk);
        } else {
            sclq = 1.f / (nq * sk);
            sclk = 1.f / (nk * sk);
        }
    }
    if (lane == 0) {
        qn2[r] = sq * sclq * sclq;
        kn2[r] = s2 * sclk * sclk;
    }
    ushort8 qo, ko;
#pragma unroll
    for (int e = 0; e < 8; e++) {
        qo[e] = f2bf(qv[e] * sclq);
        ko[e] = f2bf(kw[e] * sclk);
    }
    *(ushort8*)&qm[(size_t)r * 512 + lane * 8] = qo;
    *(ushort8*)&km[(size_t)r * 512 + lane * 8] = ko;
}

// ---------------- normalize: attnH bf16 -> attnF fp32 (zero upper-tri) ----------------
__global__ __launch_bounds__(256) void norm_attn_kernel(
    const u16* __restrict__ attnH, const float* __restrict__ lsum,
    float* __restrict__ attnF)
{
    int i = blockIdx.x, b = blockIdx.y, t = threadIdx.x;
    float inv = 1.0f / lsum[b * SEQ + i];
    const u16* rowh = attnH + ((size_t)b * SEQ + i) * SEQ;
    float* row = attnF + ((size_t)b * SEQ + i) * SEQ;
    int L = i + 1;
    int j0 = t * 8;
    float4 lo, hi;
    if (j0 + 8 <= L) {
        ushort8 h = *(const ushort8*)&rowh[j0];
        lo.x = bf2f(h[0]) * inv; lo.y = bf2f(h[1]) * inv;
        lo.z = bf2f(h[2]) * inv; lo.w = bf2f(h[3]) * inv;
        hi.x = bf2f(h[4]) * inv; hi.y = bf2f(h[5]) * inv;
        hi.z = bf2f(h[6]) * inv; hi.w = bf2f(h[7]) * inv;
    } else {
        float v[8];
#pragma unroll
        for (int e = 0; e < 8; e++)
            v[e] = (j0 + e < L) ? bf2f(rowh[j0 + e]) * inv : 0.f;
        lo = (float4){v[0], v[1], v[2], v[3]};
        hi = (float4){v[4], v[5], v[6], v[7]};
    }
    *(float4*)&row[j0] = lo;
    *(float4*)&row[j0 + 4] = hi;
}

// ---------------- launch ----------------
extern "C" void kernel_launch(void* const* d_in, const int* in_sizes, int n_in,
                              void* d_out, int out_size, void* d_ws, size_t ws_size,
                              hipStream_t stream) {
    (void)in_sizes; (void)n_in; (void)out_size; (void)ws_size;

    const float* x    = (const float*)d_in[0];
    const float* Wq   = (const float*)d_in[1];
    const float* bq   = (const float*)d_in[2];
    const float* Wk   = (const float*)d_in[3];
    const float* bk   = (const float*)d_in[4];
    const float* Wv   = (const float*)d_in[5];
    const float* bv   = (const float*)d_in[6];
    const float* curv = (const float*)d_in[7];
    const float* temp = (const float*)d_in[8];

    float* out   = (float*)d_out;                       // [4][2048][512]
    float* attnF = out + (size_t)NB * SEQ * DIM;        // [4][2048][2048]

    char* ws = (char*)d_ws;
    // layout (bytes):
    //   0        x_bf    8,388,608   (dead after QKV)
    //   8388608  Wcat    1,572,864   (dead after QKV)
    //   9961472  qkvh   25,165,824   (dead after project)
    //   35127296 qm      8,388,608
    //   43515904 km      8,388,608
    //   51904512 vT      8,388,608   (written by QKV epilogue)
    //   60293120 qn2        32,768
    //   60325888 kn2        32,768
    //   60358656 lsum       32,768
    // attnH (33,554,432) aliases [0, 33554432) — x_bf/Wcat/qkvh all dead by then.
    u16*   x_bf  = (u16*)(ws + 0);
    u16*   Wcat  = (u16*)(ws + 8388608);
    u16*   qkvh  = (u16*)(ws + 9961472);
    u16*   qm    = (u16*)(ws + 35127296);
    u16*   km    = (u16*)(ws + 43515904);
    u16*   vT    = (u16*)(ws + 51904512);
    float* qn2   = (float*)(ws + 60293120);
    float* kn2   = (float*)(ws + 60325888);
    float* lsum  = (float*)(ws + 60358656);
    u16*   attnH = (u16*)(ws + 0);

    // K0: conversions + lsum zero + out zero
    {
        int n_tot = (NB * SEQ * DIM + 3 * DIM * DIM) / 4;
        cvt_all_kernel<<<(n_tot + 255) / 256, 256, 0, stream>>>(x, Wq, Wk, Wv, x_bf, Wcat, lsum, out);
    }

    // K1: QKV GEMM (M=8192, N=1536, K=512) + bias + fused V-transpose
    gemm64_kernel<0><<<dim3(1536 / 64, 8192 / 64, 1), 256, 0, stream>>>(
        x_bf, 512, 0, Wcat, 512, 0, (void*)qkvh, 1536, 0,
        vT, nullptr, bq, bk, bv, nullptr, nullptr, nullptr, nullptr);

    // K2: projection
    project_kernel<<<NB * SEQ / 4, 256, 0, stream>>>(qkvh, qm, km, qn2, kn2, curv);

    // K3: scores + dist + exp (unnormalized bf16) + row sums
    gemm64_kernel<1><<<dim3(SEQ / 64, SEQ / 64, NB), 256, 0, stream>>>(
        qm, 512, (long long)SEQ * DIM, km, 512, (long long)SEQ * DIM,
        (void*)attnH, SEQ, (long long)SEQ * SEQ,
        nullptr, lsum, nullptr, nullptr, nullptr, qn2, kn2, curv, temp);

    // K4: PV split-K x2, atomicAdd with 1/l scaling
    gemm64_kernel<2><<<dim3(2 * DIM / 64, SEQ / 64, NB), 256, 0, stream>>>(
        attnH, SEQ, (long long)SEQ * SEQ, vT, SEQ, (long long)DIM * SEQ,
        (void*)out, DIM, (long long)SEQ * DIM,
        nullptr, lsum, nullptr, nullptr, nullptr, nullptr, nullptr, nullptr, nullptr);

    // K5: attention fp32 output from bf16 + 1/l
    norm_attn_kernel<<<dim3(SEQ, NB), 256, 0, stream>>>(attnH, lsum, attnF);
}